// Round 4
// baseline (327.832 us; speedup 1.0000x reference)
//
#include <hip/hip_runtime.h>
#include <stdint.h>

// Problem: B=32, W=16, N=256, DIM=256, GAMMA=4, V=64, TABLE=961
// out[b,w,m,vv*4+s] = sum_nn bias_table[rel_index[m,nn], s*16+w] * x[b,w,nn,vv*4+s]
//                     + token_bias[w*4+s, m]
// Device dtypes CONFIRMED (round 3 pass): fp32 tensors, int32 rel_index.
// Compute: bf16 MFMA, fp32 accumulation.

typedef __attribute__((ext_vector_type(8))) short bf16x8;
typedef __attribute__((ext_vector_type(4))) float f32x4;
typedef __attribute__((ext_vector_type(8))) unsigned short u16x8;

__device__ __forceinline__ unsigned short f2bf(float f) {
    union { float f; unsigned u; } v; v.f = f;
    unsigned u = v.u;
    u += 0x7FFFu + ((u >> 16) & 1u);          // round-nearest-even
    return (unsigned short)(u >> 16);
}

// ---------- Pass 1: gather Ab[plane=w*4+s][m][nn] bf16 into d_ws (8 MB) ----------
// Block handles 1024 consecutive elements of one plane -> bias column is
// constant per block: stage it (961 floats, 3.8 KB) into LDS once, gather local.
__global__ __launch_bounds__(256) void k_gather(
    const float* __restrict__ bt,                    // (961, 64) fp32
    const int*  __restrict__ rel_index,              // (256, 256) int32
    unsigned short* __restrict__ Ab)                 // (64, 256, 256) bf16
{
    __shared__ float colLds[961];
    const int t  = threadIdx.x;
    const int ws = blockIdx.x >> 6;                  // plane = w*4 + s
    const int colw = ((ws & 3) << 4) + (ws >> 2);    // s*16 + w
    for (int i = t; i < 961; i += 256)
        colLds[i] = bt[(i << 6) + colw];
    __syncthreads();

    const int base = (blockIdx.x * 256 + t) << 2;    // element index in Ab
    const int nn = base & 255;
    const int m  = (base >> 8) & 255;
    const int* ri = rel_index + (m << 8) + nn;
    ushort4 o;
    o.x = f2bf(colLds[ri[0]]);
    o.y = f2bf(colLds[ri[1]]);
    o.z = f2bf(colLds[ri[2]]);
    o.w = f2bf(colLds[ri[3]]);
    *(ushort4*)(Ab + base) = o;
}

// ---------- Pass 2: pipelined MFMA GEMM ----------
// grid: bx = (w*2 + mt)*32 + b (1024 blocks), block 512 threads (8 waves)
// wave = (s = wave&3, vv-half = wave>>2); per-wave tile m 128 x vv 32, K=256
// LDS (elements): As [s4][m128][nn32] @0, Xs [s4][vv64][nn32] @16384
// XOR swizzle: 16B group g of row r stored at slot g ^ ((r>>2)&3)  (lane-constant)
__global__ __launch_bounds__(512, 4) void k_main(
    const float* __restrict__ x,                     // (32,16,256,256) fp32
    const unsigned short* __restrict__ Ab,           // (64,256,256) bf16
    const float* __restrict__ token_bias,            // (64,256) fp32
    float* __restrict__ out)                         // (32,16,256,256) fp32
{
    __shared__ unsigned short lds[16384 + 8192];     // 48 KB

    const int tid  = threadIdx.x;
    const int lane = tid & 63;
    const int wave = tid >> 6;
    const int bx = blockIdx.x;
    const int b  = bx & 31;
    const int mt = (bx >> 5) & 1;
    const int w  = bx >> 6;
    const int m0 = mt << 7;

    const int sw   = wave & 3;
    const int vh   = wave >> 2;
    const int vvb  = vh << 5;
    const int col  = lane & 15;
    const int quad = lane >> 4;

    // ---- A staging: thread t covers row a_row, logical group a_g, 4 planes
    const int a_row = tid >> 2;                      // 0..127
    const int a_g   = tid & 3;                       // 16B group 0..3
    const int a_gs  = a_g ^ ((a_row >> 2) & 3);      // swizzled slot
    unsigned short* AsW = lds + (a_row << 5) + (a_gs << 3);
    const unsigned short* Ag = Ab + (w << 18) + ((m0 + a_row) << 8) + (a_g << 3);

    // ---- X staging: thread t: nn = t&31, vg = t>>5 (16 consecutive d each)
    const int x_nn = tid & 31;
    const int x_vg = tid >> 5;
    const float* Xg = x + (((b << 4) + w) << 16) + (x_nn << 8) + (x_vg << 4);
    // swizzle slot for X: (vv>>2)&3 == x_vg&3 for all 16 values of this thread
    unsigned short* XsW = lds + 16384 + (((x_nn >> 3) ^ (x_vg & 3)) << 3) + (x_nn & 7);

    f32x4 acc[8][2];
#pragma unroll
    for (int mi = 0; mi < 8; mi++) {
        acc[mi][0] = (f32x4){0.f, 0.f, 0.f, 0.f};
        acc[mi][1] = (f32x4){0.f, 0.f, 0.f, 0.f};
    }

    // fragment read pointers (swizzled slot = quad ^ ((col>>2)&3), lane-const)
    const int gsr = quad ^ ((col >> 2) & 3);
    const unsigned short* AsR = lds + (sw << 12) + (col << 5) + (gsr << 3);
    const unsigned short* XsR = lds + 16384 + (sw << 11) + ((vvb + col) << 5) + (gsr << 3);

    // ---- prologue: prefetch chunk 0
    u16x8  av[4];
    float4 xv[4];
#pragma unroll
    for (int it = 0; it < 4; it++)
        av[it] = *(const u16x8*)(Ag + (it << 16));
#pragma unroll
    for (int i = 0; i < 4; i++)
        xv[i] = *(const float4*)(Xg + (i << 2));

#pragma unroll
    for (int nc = 0; nc < 8; nc++) {
        // ---- stage prefetched regs -> LDS
#pragma unroll
        for (int it = 0; it < 4; it++)
            *(u16x8*)(AsW + (it << 12)) = av[it];
        const float* xf = (const float*)xv;
#pragma unroll
        for (int j = 0; j < 16; j++) {
            int vv = (x_vg << 2) + (j >> 2);
            XsW[((j & 3) << 11) + (vv << 5)] = f2bf(xf[j]);
        }
        __syncthreads();

        // ---- prefetch next chunk (overlaps MFMA + barrier below)
        if (nc < 7) {
#pragma unroll
            for (int it = 0; it < 4; it++)
                av[it] = *(const u16x8*)(Ag + (it << 16) + ((nc + 1) << 5));
#pragma unroll
            for (int i = 0; i < 4; i++)
                xv[i] = *(const float4*)(Xg + ((nc + 1) << 13) + (i << 2));
        }

        // ---- compute chunk nc
        bf16x8 bfr0 = *(const bf16x8*)(XsR);
        bf16x8 bfr1 = *(const bf16x8*)(XsR + 512);
#pragma unroll
        for (int mi = 0; mi < 8; mi++) {
            bf16x8 afr = *(const bf16x8*)(AsR + (mi << 9));
            acc[mi][0] = __builtin_amdgcn_mfma_f32_16x16x32_bf16(afr, bfr0, acc[mi][0], 0, 0, 0);
            acc[mi][1] = __builtin_amdgcn_mfma_f32_16x16x32_bf16(afr, bfr1, acc[mi][1], 0, 0, 0);
        }
        __syncthreads();
    }

    // ---- epilogue: D[row=m=quad*4+r][col=vv], + token_bias[w*4+s, m]
    const float* tb = token_bias + (((w << 2) + sw) << 8) + m0;
    float* ob = out + (((b << 4) + w) << 16) + (m0 << 8) + sw;
#pragma unroll
    for (int mi = 0; mi < 8; mi++) {
#pragma unroll
        for (int r = 0; r < 4; r++) {
            int m = (mi << 4) + (quad << 2) + r;
            float bias = tb[m];
#pragma unroll
            for (int vi = 0; vi < 2; vi++) {
                int vv = vvb + (vi << 4) + col;
                ob[(m << 8) + (vv << 2)] = acc[mi][vi][r] + bias;
            }
        }
    }
}

extern "C" void kernel_launch(void* const* d_in, const int* in_sizes, int n_in,
                              void* d_out, int out_size, void* d_ws, size_t ws_size,
                              hipStream_t stream) {
    const float* x          = (const float*)d_in[0];
    const float* bias_table = (const float*)d_in[1];
    const float* token_bias = (const float*)d_in[2];
    const int*   rel_index  = (const int*)d_in[3];
    unsigned short* Ab = (unsigned short*)d_ws;      // 8 MB scratch
    float* out = (float*)d_out;

    hipLaunchKernelGGL(k_gather, dim3(4096), dim3(256), 0, stream,
                       bias_table, rel_index, Ab);
    hipLaunchKernelGGL(k_main, dim3(1024), dim3(512), 0, stream,
                       x, Ab, token_bias, out);
}